// Round 8
// baseline (210.879 us; speedup 1.0000x reference)
//
#include <hip/hip_runtime.h>
#include <hip/hip_bf16.h>

typedef __attribute__((ext_vector_type(8))) short short8;
typedef __attribute__((ext_vector_type(4))) short s16x4;
typedef __attribute__((ext_vector_type(4))) float f32x4;
typedef unsigned short u16;

// round-to-nearest-even fp32 -> bf16
__device__ inline u16 f2bf(float f) {
    union { float f; unsigned u; } x{f};
    unsigned r = (x.u + 0x7fff + ((x.u >> 16) & 1)) >> 16;
    return (u16)r;
}

// pack two fp32 -> packed bf16 pair (round-half-up via +0x8000, then v_perm)
__device__ inline unsigned pkbf(float hi, float lo) {
    unsigned a = __builtin_bit_cast(unsigned, hi) + 0x8000u;
    unsigned b = __builtin_bit_cast(unsigned, lo) + 0x8000u;
    return __builtin_amdgcn_perm(a, b, 0x07060302u);
}

// async 16B global -> LDS (wave-uniform base + lane*16 layout)
__device__ inline void glds16(const u16* g, u16* l) {
    __builtin_amdgcn_global_load_lds(
        (const __attribute__((address_space(1))) void*)g,
        (__attribute__((address_space(3))) void*)l, 16, 0, 0);
}

// ---------------- fused prep: cvt x -> bf16 | transpose w_in | w_out --------
__global__ __launch_bounds__(256) void prep(const float* __restrict__ x,
                                            const float* __restrict__ w_in,
                                            const float* __restrict__ w_out,
                                            u16* __restrict__ Xb,
                                            u16* __restrict__ WtIn,
                                            u16* __restrict__ WtOut) {
    __shared__ float tile[32][33];
    int bx = blockIdx.x, tid = threadIdx.x;
    if (bx < 4096) {
        int i = (bx * 256 + tid) * 4;
        float4 v = *(const float4*)&x[i];
        uint2 o;
        o.x = (unsigned)f2bf(v.x) | ((unsigned)f2bf(v.y) << 16);
        o.y = (unsigned)f2bf(v.z) | ((unsigned)f2bf(v.w) << 16);
        *(uint2*)&Xb[i] = o;
        return;
    }
    const float* W; u16* Wt; int K, N, n0, k0;
    if (bx < 7168) {
        int b2 = bx - 4096;                 // w_in: K=1024, N=3072
        W = w_in; Wt = WtIn; K = 1024; N = 3072;
        n0 = (b2 % 96) * 32; k0 = (b2 / 96) * 32;
    } else {
        int b3 = bx - 7168;                 // w_out: K=1024, N=1024
        W = w_out; Wt = WtOut; K = 1024; N = 1024;
        n0 = (b3 & 31) * 32; k0 = (b3 >> 5) * 32;
    }
    int tx = tid & 31, ty = tid >> 5;
    for (int i = 0; i < 32; i += 8)
        tile[ty + i][tx] = W[(size_t)(k0 + ty + i) * N + n0 + tx];
    __syncthreads();
    for (int i = 0; i < 32; i += 8)
        Wt[(size_t)(n0 + ty + i) * K + k0 + tx] = f2bf(tile[tx][ty + i]);
}

// ---------------- GEMM: C[M][N] = A[M][K] @ Bt[N][K]^T + bias ---------------
// 128x128 2-barrier structure (616 TF on gemm1 = its structural ceiling at
// K=1024). gemm1: vt fuses the V^T scatter. gemm2 uses 64x128 (2 blocks/CU).
#define BK 64
template<int TBM, int TBN>
__global__ __launch_bounds__(256) void gemm_bt(const u16* __restrict__ A,
                                               const u16* __restrict__ Bt,
                                               const float* __restrict__ bias,
                                               void* __restrict__ C,
                                               int M, int N, int K, int c_is_f32,
                                               int qcols, float qscale,
                                               u16* __restrict__ vt, int vcol0) {
    __shared__ u16 smem[TBM * BK + TBN * BK + 2048];
    u16* As = smem;
    u16* Bs = smem + TBM * BK;

    int tid = threadIdx.x;
    int wave = tid >> 6, lane = tid & 63;
    int quad = lane >> 4, l16 = lane & 15;
    int wm = (wave >> 1) * (TBM / 2), wn = (wave & 1) * (TBN / 2);
    constexpr int MI = TBM / 32, NJ = TBN / 32;

    int nm = M / TBM, nn = N / TBN;
    const int GM = 8;
    int per_group = GM * nn;
    int group = blockIdx.x / per_group;
    int rem = blockIdx.x % per_group;
    int first_m = group * GM;
    int gsz = (nm - first_m < GM) ? (nm - first_m) : GM;
    int m0 = (first_m + rem % gsz) * TBM;
    int n0 = (rem / gsz) * TBN;

    f32x4 acc[MI][NJ] = {};

    for (int k0 = 0; k0 < K; k0 += BK) {
        __syncthreads();
        for (int i = 0; i < TBM * 8 / 256; i++) {
            int c = tid + i * 256;
            int r = c >> 3, cc = c & 7;
            int gsrc = (cc ^ (r & 7)) * 8;          // XOR swizzle
            glds16(&A[(size_t)(m0 + r) * K + k0 + gsrc], As + c * 8);
        }
        for (int i = 0; i < TBN * 8 / 256; i++) {
            int c = tid + i * 256;
            int r = c >> 3, cc = c & 7;
            int gsrc = (cc ^ (r & 7)) * 8;
            glds16(&Bt[(size_t)(n0 + r) * K + k0 + gsrc], Bs + c * 8);
        }
        __syncthreads();
        for (int ks = 0; ks < 2; ks++) {
            short8 af[MI], bf[NJ];
            for (int i = 0; i < MI; i++) {
                int row = wm + i * 16 + l16;
                int slot = (ks * 4 + quad) ^ (row & 7);
                af[i] = *(short8*)&As[row * BK + slot * 8];
            }
            for (int j = 0; j < NJ; j++) {
                int row = wn + j * 16 + l16;
                int slot = (ks * 4 + quad) ^ (row & 7);
                bf[j] = *(short8*)&Bs[row * BK + slot * 8];
            }
            for (int i = 0; i < MI; i++)
                for (int j = 0; j < NJ; j++)
                    acc[i][j] = __builtin_amdgcn_mfma_f32_16x16x32_bf16(
                        af[i], bf[j], acc[i][j], 0, 0, 0);
        }
    }

    if (c_is_f32) {
        for (int i = 0; i < MI; i++)
            for (int j = 0; j < NJ; j++) {
                int col = n0 + wn + j * 16 + l16;
                float bv = bias ? bias[col] : 0.f;
                for (int r = 0; r < 4; r++) {
                    int row = m0 + wm + i * 16 + quad * 4 + r;
                    ((float*)C)[(size_t)row * N + col] = acc[i][j][r] + bv;
                }
            }
    } else {
        __syncthreads();
        u16 (*buf)[136] = (u16(*)[136])smem;
        for (int i = 0; i < MI; i++)
            for (int j = 0; j < NJ; j++) {
                int col = wn + j * 16 + l16;
                float bv = bias ? bias[n0 + col] : 0.f;
                float scl = (n0 + col < qcols) ? qscale : 1.f;
                for (int r = 0; r < 4; r++)
                    buf[wm + i * 16 + quad * 4 + r][col] =
                        f2bf((acc[i][j][r] + bv) * scl);
            }
        __syncthreads();
        u16* Cb = (u16*)C;
        for (int it = 0; it < TBM * 16 / 256; it++) {
            int c = tid + it * 256;
            int row = c / (TBN / 8), k8 = c % (TBN / 8);
            uint4 v = *(uint4*)&buf[row][k8 * 8];
            *(uint4*)&Cb[(size_t)(m0 + row) * N + n0 + k8 * 8] = v;
        }
        // fused V^T scatter: vt[b, h, dh, S] <- buf^T for V-range columns.
        if (vt && n0 >= vcol0) {
            int b = m0 >> 11, s0 = m0 & 2047;
            int hbase = (n0 - vcol0) >> 6;
            for (int pass = 0; pass < TBN / 16; pass++) {
                int col = pass * 16 + (tid >> 4);
                int so = (tid & 15) * 8;
                alignas(16) u16 tmp[8];
                for (int r = 0; r < 8; r++) tmp[r] = buf[so + r][col];
                int h = hbase + (col >> 6), dh = col & 63;
                *(uint4*)&vt[(size_t)((b * 16 + h) * 64 + dh) * 2048 + s0 + so] =
                    __builtin_bit_cast(uint4, tmp);
            }
        }
    }
}

// ---------------- flash attention (causal), k-split partials ----------------
// Round 15/16. Theory: the kernel was TLP-starved — 512 blocks x 4 waves =
// 2048 waves / 1024 SIMDs = 2 waves/SIMD, hard-capped by the grid (65536
// q-rows / 32 q/wave), so the serial QK->exp2->pack->PV chain left both
// pipes ~25% busy. Fix: split each (bh, qt) tile's k-range into TWO equal
// halves (qt+1 tiles of 64 k each) on independent blocks — valid because
// no-max softmax tile contributions are order-independent sums. Each block
// writes f32 partials (O, l); combine computes out=(O0+O1)/(l0+l1).
// Single-chain dbuf -> LDS 32 KB -> 4 blocks/CU = 4 waves/SIMD from 4
// INDEPENDENT barrier domains. Per-CU load = 34 tiles, exactly balanced.
__global__ __launch_bounds__(256, 4) void attn_kernel(const u16* __restrict__ qkv,
                                                      const u16* __restrict__ VT,
                                                      float* __restrict__ Op,
                                                      float* __restrict__ lp) {
    const int S = 2048, D = 1024, stride = 3072;
    int idx = blockIdx.x;                 // 1024 blocks
    int half = idx >> 9;                  // k-range half
    int r9 = idx & 511;
    int slot = r9 >> 8;                   // heavy/light pairing
    int r8 = r9 & 255;
    int p = r8 >> 5, bh = r8 & 31;
    int qt = slot ? p : 15 - p;           // q-tile (128 rows) index
    int b = bh >> 4, h = bh & 15;
    int tid = threadIdx.x;                // 256
    int wave = tid >> 6, lane = tid & 63;
    int quad = lane >> 4, l16 = lane & 15;

    __shared__ u16 Klds[2][64 * 64];      // [dbuf]; XOR-swizzled rows (16 KB)
    __shared__ u16 Vlds[2][64 * 64];      // (16 KB)

    const u16* Qp = qkv + (size_t)(b * S) * stride + h * 64;
    const u16* Kp = Qp + D;
    const u16* Vtp = VT + (size_t)bh * 64 * S;

    // Q fragments: [q-half][k-half]; wave owns rows qt*128 + wave*32 + 0..31
    short8 qf[2][2];
    for (int qh = 0; qh < 2; qh++) {
        int qrow = qt * 128 + wave * 32 + qh * 16 + l16;
        qf[qh][0] = *(const short8*)&Qp[(size_t)qrow * stride + quad * 8];
        qf[qh][1] = *(const short8*)&Qp[(size_t)qrow * stride + 32 + quad * 8];
    }

    auto stage = [&](int kt, int bsel) {
        for (int i = 0; i < 2; i++) {
            int c = tid + i * 256;        // 512 chunks of 16B each for K and V
            int rr = c >> 3, cc = c & 7;
            int gsrc = (cc ^ (rr & 7)) * 8;
            glds16(&Kp[(size_t)(kt * 64 + rr) * stride + gsrc],
                   &Klds[bsel][c * 8]);
            glds16(&Vtp[(size_t)rr * S + kt * 64 + gsrc],
                   &Vlds[bsel][c * 8]);
        }
    };

    int k0t = half * (qt + 1);            // this block's 64-k tile range
    int k1t = k0t + (qt + 1);
    stage(k0t, 0);

    f32x4 O[4][2] = {};                   // [db][qh], O^T fragments
    float ls[2] = {0.f, 0.f};             // row-sum partials per q-half

    for (int kt = k0t; kt < k1t; kt++) {
        int cur = (kt - k0t) & 1;
        __syncthreads();                  // readers done w/ cur^1 + DMA drained
        if (kt + 1 < k1t) stage(kt + 1, cur ^ 1);
        bool maskt = (kt >= 2 * qt);      // tiles straddling the diagonal

        // ---- QK^T -> st[qh][nb] (S^T: lane q=l16, k=nb*16+quad*4+r)
        short8 kf[4][2];
        for (int nb = 0; nb < 4; nb++) {
            int rr = nb * 16 + l16;
            kf[nb][0] = *(short8*)&Klds[cur][rr * 64 + ((0 + quad) ^ (rr & 7)) * 8];
            kf[nb][1] = *(short8*)&Klds[cur][rr * 64 + ((4 + quad) ^ (rr & 7)) * 8];
        }
        f32x4 st[2][4];
        __builtin_amdgcn_s_setprio(1);
        for (int qh = 0; qh < 2; qh++)
            for (int nb = 0; nb < 4; nb++) {
                f32x4 t = {};
                t = __builtin_amdgcn_mfma_f32_16x16x32_bf16(
                    kf[nb][0], qf[qh][0], t, 0, 0, 0);
                t = __builtin_amdgcn_mfma_f32_16x16x32_bf16(
                    kf[nb][1], qf[qh][1], t, 0, 0, 0);
                st[qh][nb] = t;
            }
        __builtin_amdgcn_s_setprio(0);

        // ---- softmax numerators + pack (Q pre-scaled by 1/8*log2e in gemm1)
        s16x4 pf[2][4];
        for (int qh = 0; qh < 2; qh++) {
            if (maskt) {
                int qabs = qt * 128 + wave * 32 + qh * 16 + l16;
                for (int nb = 0; nb < 4; nb++) {
                    int kb0 = kt * 64 + nb * 16 + quad * 4;
                    for (int r = 0; r < 4; r++) {
                        float e = __builtin_amdgcn_exp2f(st[qh][nb][r]);
                        st[qh][nb][r] = (kb0 + r <= qabs) ? e : 0.f;
                    }
                }
            } else {
                for (int nb = 0; nb < 4; nb++)
                    for (int r = 0; r < 4; r++)
                        st[qh][nb][r] = __builtin_amdgcn_exp2f(st[qh][nb][r]);
            }
            for (int nb = 0; nb < 4; nb++) {
                ls[qh] += (st[qh][nb][0] + st[qh][nb][1]) +
                          (st[qh][nb][2] + st[qh][nb][3]);
                uint2 pk;
                pk.x = pkbf(st[qh][nb][1], st[qh][nb][0]);
                pk.y = pkbf(st[qh][nb][3], st[qh][nb][2]);
                pf[qh][nb] = __builtin_bit_cast(s16x4, pk);
            }
        }

        // ---- PV (O^T accumulate; V frag shared by both q-halves)
        __builtin_amdgcn_s_setprio(1);
        for (int db = 0; db < 4; db++) {
            int rr = db * 16 + l16;
            for (int kc = 0; kc < 4; kc++) {
                int g = kc * 2 + (quad >> 1);
                int sl = g ^ (rr & 7);
                int off = rr * 64 + sl * 8 + (quad & 1) * 4;
                s16x4 vf = *(s16x4*)&Vlds[cur][off];
                for (int qh = 0; qh < 2; qh++)
                    O[db][qh] = __builtin_amdgcn_mfma_f32_16x16x16bf16_1k(
                        vf, pf[qh][kc], O[db][qh], 0, 0, 0);
            }
        }
        __builtin_amdgcn_s_setprio(0);
    }

    // partial epilogue: write f32 O^T tile + row-sums (no division here)
    int e = (bh * 16 + qt) * 2 + half;
    float* Ope = Op + (size_t)e * (128 * 64);
    for (int qh = 0; qh < 2; qh++) {
        float v = ls[qh];
        v += __shfl_xor(v, 16);
        v += __shfl_xor(v, 32);           // full row sum for q=l16
        if (lane < 16)
            lp[e * 128 + wave * 32 + qh * 16 + lane] = v;
        int row = wave * 32 + qh * 16 + l16;
        for (int db = 0; db < 4; db++)
            *(f32x4*)&Ope[row * 64 + db * 16 + quad * 4] = O[db][qh];
    }
}

// ---------------- combine: out = (O0 + O1) / (l0 + l1), bf16 ----------------
__global__ __launch_bounds__(256) void combine(const float* __restrict__ Op,
                                               const float* __restrict__ lp,
                                               u16* __restrict__ out) {
    int cb = blockIdx.x;                  // 512 = (qt, bh)
    int bh = cb & 31, qt = cb >> 5;
    int b = bh >> 4, h = bh & 15;
    int tid = threadIdx.x;
    int row = tid >> 1, c0 = (tid & 1) * 32;
    int e = (bh * 16 + qt) * 2;
    float l = lp[e * 128 + row] + lp[(e + 1) * 128 + row];
    float rinv = 1.f / l;
    const float* p0 = Op + (size_t)e * (128 * 64) + row * 64 + c0;
    const float* p1 = p0 + 128 * 64;
    u16* po = out + ((size_t)(b * 2048 + qt * 128 + row)) * 1024 + h * 64 + c0;
    for (int d = 0; d < 32; d += 8) {
        f32x4 a0 = *(const f32x4*)&p0[d], a1 = *(const f32x4*)&p0[d + 4];
        f32x4 b0 = *(const f32x4*)&p1[d], b1 = *(const f32x4*)&p1[d + 4];
        uint4 o;
        o.x = pkbf((a0[1] + b0[1]) * rinv, (a0[0] + b0[0]) * rinv);
        o.y = pkbf((a0[3] + b0[3]) * rinv, (a0[2] + b0[2]) * rinv);
        o.z = pkbf((a1[1] + b1[1]) * rinv, (a1[0] + b1[0]) * rinv);
        o.w = pkbf((a1[3] + b1[3]) * rinv, (a1[2] + b1[2]) * rinv);
        *(uint4*)&po[d] = o;
    }
}

// ---------------------------------------------------------------------------
extern "C" void kernel_launch(void* const* d_in, const int* in_sizes, int n_in,
                              void* d_out, int out_size, void* d_ws, size_t ws_size,
                              hipStream_t stream) {
    const float* x     = (const float*)d_in[0];
    const float* w_in  = (const float*)d_in[1];
    const float* b_in  = (const float*)d_in[2];
    const float* w_out = (const float*)d_in[3];
    const float* b_out = (const float*)d_in[4];

    const int Bsz = 2, S = 2048, D = 1024, H = 16;
    const int M = Bsz * S;
    const int N1 = 3 * D;
    const float sc = 0.125f * 1.44269504f;  // 1/sqrt(64) * log2(e)

    u16* ws    = (u16*)d_ws;
    u16* Xb    = ws;
    u16* WtIn  = Xb + (size_t)M * D;
    u16* WtOut = WtIn + (size_t)N1 * D;
    u16* qkvb  = WtOut + (size_t)D * D;
    u16* attnb = qkvb + (size_t)M * N1;
    u16* Vt    = attnb + (size_t)M * D;    // fresh memory (gemm1 reads Xb)
    float* Op  = (float*)(Vt + (size_t)Bsz * H * 64 * S);  // 32 MB partials
    float* lp  = Op + (size_t)1024 * 128 * 64;             // 512 KB row sums

    prep<<<8192, 256, 0, stream>>>(x, w_in, w_out, Xb, WtIn, WtOut);
    gemm_bt<128, 128><<<(M / 128) * (N1 / 128), 256, 0, stream>>>(
        Xb, WtIn, b_in, qkvb, M, N1, D, 0, D, sc, Vt, 2048);
    attn_kernel<<<1024, 256, 0, stream>>>(qkvb, Vt, Op, lp);
    combine<<<512, 256, 0, stream>>>(Op, lp, attnb);
    gemm_bt<64, 128><<<(M / 64) * (D / 128), 256, 0, stream>>>(
        attnb, WtOut, b_out, d_out, M, D, D, 1, 0, 1.f, nullptr, 1 << 30);
}

// Round 9
// 172.903 us; speedup vs baseline: 1.2196x; 1.2196x over previous
//
#include <hip/hip_runtime.h>
#include <hip/hip_bf16.h>

typedef __attribute__((ext_vector_type(8))) short short8;
typedef __attribute__((ext_vector_type(4))) short s16x4;
typedef __attribute__((ext_vector_type(4))) float f32x4;
typedef unsigned short u16;

// round-to-nearest-even fp32 -> bf16
__device__ inline u16 f2bf(float f) {
    union { float f; unsigned u; } x{f};
    unsigned r = (x.u + 0x7fff + ((x.u >> 16) & 1)) >> 16;
    return (u16)r;
}

// pack two fp32 -> packed bf16 pair (round-half-up via +0x8000, then v_perm)
__device__ inline unsigned pkbf(float hi, float lo) {
    unsigned a = __builtin_bit_cast(unsigned, hi) + 0x8000u;
    unsigned b = __builtin_bit_cast(unsigned, lo) + 0x8000u;
    return __builtin_amdgcn_perm(a, b, 0x07060302u);
}

// async 16B global -> LDS (wave-uniform base + lane*16 layout)
__device__ inline void glds16(const u16* g, u16* l) {
    __builtin_amdgcn_global_load_lds(
        (const __attribute__((address_space(1))) void*)g,
        (__attribute__((address_space(3))) void*)l, 16, 0, 0);
}

// ---------------- fused prep: cvt x -> bf16 | transpose w_in | w_out --------
__global__ __launch_bounds__(256) void prep(const float* __restrict__ x,
                                            const float* __restrict__ w_in,
                                            const float* __restrict__ w_out,
                                            u16* __restrict__ Xb,
                                            u16* __restrict__ WtIn,
                                            u16* __restrict__ WtOut) {
    __shared__ float tile[32][33];
    int bx = blockIdx.x, tid = threadIdx.x;
    if (bx < 4096) {
        int i = (bx * 256 + tid) * 4;
        float4 v = *(const float4*)&x[i];
        uint2 o;
        o.x = (unsigned)f2bf(v.x) | ((unsigned)f2bf(v.y) << 16);
        o.y = (unsigned)f2bf(v.z) | ((unsigned)f2bf(v.w) << 16);
        *(uint2*)&Xb[i] = o;
        return;
    }
    const float* W; u16* Wt; int K, N, n0, k0;
    if (bx < 7168) {
        int b2 = bx - 4096;                 // w_in: K=1024, N=3072
        W = w_in; Wt = WtIn; K = 1024; N = 3072;
        n0 = (b2 % 96) * 32; k0 = (b2 / 96) * 32;
    } else {
        int b3 = bx - 7168;                 // w_out: K=1024, N=1024
        W = w_out; Wt = WtOut; K = 1024; N = 1024;
        n0 = (b3 & 31) * 32; k0 = (b3 >> 5) * 32;
    }
    int tx = tid & 31, ty = tid >> 5;
    for (int i = 0; i < 32; i += 8)
        tile[ty + i][tx] = W[(size_t)(k0 + ty + i) * N + n0 + tx];
    __syncthreads();
    for (int i = 0; i < 32; i += 8)
        Wt[(size_t)(n0 + ty + i) * K + k0 + tx] = f2bf(tile[tx][ty + i]);
}

// ---------------- GEMM: C[M][N] = A[M][K] @ Bt[N][K]^T + bias ---------------
// 128x128 2-barrier structure (616 TF on gemm1 = its structural ceiling at
// K=1024; both 8-phase ports regressed — rounds 12/13). gemm1: vt fuses the
// V^T scatter. gemm2 uses 64x128 (512 blocks = 2/CU; 128x128 was 1/CU).
#define BK 64
template<int TBM, int TBN>
__global__ __launch_bounds__(256) void gemm_bt(const u16* __restrict__ A,
                                               const u16* __restrict__ Bt,
                                               const float* __restrict__ bias,
                                               void* __restrict__ C,
                                               int M, int N, int K, int c_is_f32,
                                               int qcols, float qscale,
                                               u16* __restrict__ vt, int vcol0) {
    __shared__ u16 smem[TBM * BK + TBN * BK + 2048];
    u16* As = smem;
    u16* Bs = smem + TBM * BK;

    int tid = threadIdx.x;
    int wave = tid >> 6, lane = tid & 63;
    int quad = lane >> 4, l16 = lane & 15;
    int wm = (wave >> 1) * (TBM / 2), wn = (wave & 1) * (TBN / 2);
    constexpr int MI = TBM / 32, NJ = TBN / 32;

    int nm = M / TBM, nn = N / TBN;
    const int GM = 8;
    int per_group = GM * nn;
    int group = blockIdx.x / per_group;
    int rem = blockIdx.x % per_group;
    int first_m = group * GM;
    int gsz = (nm - first_m < GM) ? (nm - first_m) : GM;
    int m0 = (first_m + rem % gsz) * TBM;
    int n0 = (rem / gsz) * TBN;

    f32x4 acc[MI][NJ] = {};

    for (int k0 = 0; k0 < K; k0 += BK) {
        __syncthreads();
        for (int i = 0; i < TBM * 8 / 256; i++) {
            int c = tid + i * 256;
            int r = c >> 3, cc = c & 7;
            int gsrc = (cc ^ (r & 7)) * 8;          // XOR swizzle
            glds16(&A[(size_t)(m0 + r) * K + k0 + gsrc], As + c * 8);
        }
        for (int i = 0; i < TBN * 8 / 256; i++) {
            int c = tid + i * 256;
            int r = c >> 3, cc = c & 7;
            int gsrc = (cc ^ (r & 7)) * 8;
            glds16(&Bt[(size_t)(n0 + r) * K + k0 + gsrc], Bs + c * 8);
        }
        __syncthreads();
        for (int ks = 0; ks < 2; ks++) {
            short8 af[MI], bf[NJ];
            for (int i = 0; i < MI; i++) {
                int row = wm + i * 16 + l16;
                int slot = (ks * 4 + quad) ^ (row & 7);
                af[i] = *(short8*)&As[row * BK + slot * 8];
            }
            for (int j = 0; j < NJ; j++) {
                int row = wn + j * 16 + l16;
                int slot = (ks * 4 + quad) ^ (row & 7);
                bf[j] = *(short8*)&Bs[row * BK + slot * 8];
            }
            for (int i = 0; i < MI; i++)
                for (int j = 0; j < NJ; j++)
                    acc[i][j] = __builtin_amdgcn_mfma_f32_16x16x32_bf16(
                        af[i], bf[j], acc[i][j], 0, 0, 0);
        }
    }

    if (c_is_f32) {
        for (int i = 0; i < MI; i++)
            for (int j = 0; j < NJ; j++) {
                int col = n0 + wn + j * 16 + l16;
                float bv = bias ? bias[col] : 0.f;
                for (int r = 0; r < 4; r++) {
                    int row = m0 + wm + i * 16 + quad * 4 + r;
                    ((float*)C)[(size_t)row * N + col] = acc[i][j][r] + bv;
                }
            }
    } else {
        __syncthreads();
        u16 (*buf)[136] = (u16(*)[136])smem;
        for (int i = 0; i < MI; i++)
            for (int j = 0; j < NJ; j++) {
                int col = wn + j * 16 + l16;
                float bv = bias ? bias[n0 + col] : 0.f;
                float scl = (n0 + col < qcols) ? qscale : 1.f;
                for (int r = 0; r < 4; r++)
                    buf[wm + i * 16 + quad * 4 + r][col] =
                        f2bf((acc[i][j][r] + bv) * scl);
            }
        __syncthreads();
        u16* Cb = (u16*)C;
        for (int it = 0; it < TBM * 16 / 256; it++) {
            int c = tid + it * 256;
            int row = c / (TBN / 8), k8 = c % (TBN / 8);
            uint4 v = *(uint4*)&buf[row][k8 * 8];
            *(uint4*)&Cb[(size_t)(m0 + row) * N + n0 + k8 * 8] = v;
        }
        // fused V^T scatter: vt[b, h, dh, S] <- buf^T for V-range columns.
        if (vt && n0 >= vcol0) {
            int b = m0 >> 11, s0 = m0 & 2047;
            int hbase = (n0 - vcol0) >> 6;
            for (int pass = 0; pass < TBN / 16; pass++) {
                int col = pass * 16 + (tid >> 4);
                int so = (tid & 15) * 8;
                alignas(16) u16 tmp[8];
                for (int r = 0; r < 8; r++) tmp[r] = buf[so + r][col];
                int h = hbase + (col >> 6), dh = col & 63;
                *(uint4*)&vt[(size_t)((b * 16 + h) * 64 + dh) * 2048 + s0 + so] =
                    __builtin_bit_cast(uint4, tmp);
            }
        }
    }
}

// ---------------- flash attention (causal), 32 q-rows per wave --------------
// Session-best structure (round 9/10): dual k-tile chains per iteration give
// intra-wave ILP (QK(B)+PV(A) MFMA cluster overlaps chain-B softmax VALU);
// O^T epilogue (PV operand-swapped) removes the Obuf repack; 512 blocks x
// 256 thr, heavy/light causal pairing, 64 KB LDS -> 2 independent blocks/CU.
// Round-15 k-split (4 blocks/CU, single chain, f32 partials) REGRESSED
// (42 -> 65us, MfmaUtil 21 -> 15.5%): intra-wave dual-chain ILP beats
// cross-block TLP here; do not remove it.
__global__ __launch_bounds__(256, 2) void attn_kernel(const u16* __restrict__ qkv,
                                                      const u16* __restrict__ VT,
                                                      u16* __restrict__ out) {
    const int S = 2048, D = 1024, stride = 3072;
    int idx = blockIdx.x;                 // 512 blocks
    int slot = idx >> 8;                  // 0: heavy half, 1: light half
    int r5 = idx & 255;
    int p = r5 >> 5, bh = r5 & 31;
    int qt = slot ? p : 15 - p;           // q-tile (128 rows) index
    int b = bh >> 4, h = bh & 15;
    int tid = threadIdx.x;                // 256
    int wave = tid >> 6, lane = tid & 63;
    int quad = lane >> 4, l16 = lane & 15;

    __shared__ u16 Klds[2][2][64 * 64];   // [dbuf][chain]; XOR-swizzled rows
    __shared__ u16 Vlds[2][2][64 * 64];

    const u16* Qp = qkv + (size_t)(b * S) * stride + h * 64;
    const u16* Kp = Qp + D;
    const u16* Vtp = VT + (size_t)bh * 64 * S;

    // Q fragments: [q-half][k-half]; wave owns rows qt*128 + wave*32 + 0..31
    short8 qf[2][2];
    for (int qh = 0; qh < 2; qh++) {
        int qrow = qt * 128 + wave * 32 + qh * 16 + l16;
        qf[qh][0] = *(const short8*)&Qp[(size_t)qrow * stride + quad * 8];
        qf[qh][1] = *(const short8*)&Qp[(size_t)qrow * stride + 32 + quad * 8];
    }

    auto stage = [&](int kt, int bsel, int ch) {
        for (int i = 0; i < 2; i++) {
            int c = tid + i * 256;        // 512 chunks of 16B each for K and V
            int rr = c >> 3, cc = c & 7;
            int gsrc = (cc ^ (rr & 7)) * 8;
            glds16(&Kp[(size_t)(kt * 64 + rr) * stride + gsrc],
                   &Klds[bsel][ch][c * 8]);
            glds16(&Vtp[(size_t)rr * S + kt * 64 + gsrc],
                   &Vlds[bsel][ch][c * 8]);
        }
    };

    stage(0, 0, 0);
    stage(1, 0, 1);

    f32x4 O[4][2] = {};                   // [db][qh], O^T fragments
    float ls[2] = {0.f, 0.f};             // row-sum partials per q-half

    int np = qt + 1;                      // pairs of 64-k tiles (exact causal)
    for (int j = 0; j < np; j++) {
        int cur = j & 1;
        __syncthreads();                  // drains DMA for this pair
        if (j + 1 < np) {
            stage(2 * (j + 1), cur ^ 1, 0);
            stage(2 * (j + 1) + 1, cur ^ 1, 1);
        }
        bool last = (j == qt);

        // ---- QK^T for one chain -> st[qh][nb]
        auto qk = [&](int ch, f32x4 st[2][4]) {
            short8 kf[4][2];
            for (int nb = 0; nb < 4; nb++) {
                int rr = nb * 16 + l16;
                int s0 = ((0 + quad) ^ (rr & 7)) * 8;
                int s1 = ((4 + quad) ^ (rr & 7)) * 8;
                kf[nb][0] = *(short8*)&Klds[cur][ch][rr * 64 + s0];
                kf[nb][1] = *(short8*)&Klds[cur][ch][rr * 64 + s1];
            }
            for (int qh = 0; qh < 2; qh++)
                for (int nb = 0; nb < 4; nb++) {
                    f32x4 t = {};
                    t = __builtin_amdgcn_mfma_f32_16x16x32_bf16(
                        kf[nb][0], qf[qh][0], t, 0, 0, 0);
                    t = __builtin_amdgcn_mfma_f32_16x16x32_bf16(
                        kf[nb][1], qf[qh][1], t, 0, 0, 0);
                    st[qh][nb] = t;
                }
        };
        // ---- softmax numerators + pack for one chain
        auto sm = [&](int ch, f32x4 st[2][4], s16x4 pfc[2][4]) {
            for (int qh = 0; qh < 2; qh++) {
                if (last) {
                    int qabs = qt * 128 + wave * 32 + qh * 16 + l16;
                    for (int nb = 0; nb < 4; nb++) {
                        int kb0 = (2 * j + ch) * 64 + nb * 16 + quad * 4;
                        for (int r = 0; r < 4; r++) {
                            float e = __builtin_amdgcn_exp2f(st[qh][nb][r]);
                            st[qh][nb][r] = (kb0 + r <= qabs) ? e : 0.f;
                        }
                    }
                } else {
                    for (int nb = 0; nb < 4; nb++)
                        for (int r = 0; r < 4; r++)
                            st[qh][nb][r] = __builtin_amdgcn_exp2f(st[qh][nb][r]);
                }
                for (int nb = 0; nb < 4; nb++) {
                    ls[qh] += (st[qh][nb][0] + st[qh][nb][1]) +
                              (st[qh][nb][2] + st[qh][nb][3]);
                    uint2 pk;
                    pk.x = pkbf(st[qh][nb][1], st[qh][nb][0]);
                    pk.y = pkbf(st[qh][nb][3], st[qh][nb][2]);
                    pfc[qh][nb] = __builtin_bit_cast(s16x4, pk);
                }
            }
        };
        // ---- PV for one chain (O^T accumulate)
        auto pv = [&](int ch, s16x4 pfc[2][4]) {
            for (int db = 0; db < 4; db++) {
                int rr = db * 16 + l16;
                for (int kc = 0; kc < 4; kc++) {
                    int g = kc * 2 + (quad >> 1);
                    int sl = g ^ (rr & 7);
                    int off = rr * 64 + sl * 8 + (quad & 1) * 4;
                    s16x4 vf = *(s16x4*)&Vlds[cur][ch][off];
                    for (int qh = 0; qh < 2; qh++)
                        O[db][qh] = __builtin_amdgcn_mfma_f32_16x16x16bf16_1k(
                            vf, pfc[qh][kc], O[db][qh], 0, 0, 0);
                }
            }
        };

        f32x4 stA[2][4], stB[2][4];
        s16x4 pfA[2][4], pfB[2][4];

        __builtin_amdgcn_s_setprio(1);
        qk(0, stA);
        __builtin_amdgcn_s_setprio(0);
        sm(0, stA, pfA);
        __builtin_amdgcn_s_setprio(1);
        qk(1, stB);                       // MFMA cluster: chain-B QK ...
        pv(0, pfA);                       // ... + chain-A PV (independent of
        __builtin_amdgcn_s_setprio(0);    //     chain-B softmax -> overlaps it)
        sm(1, stB, pfB);
        __builtin_amdgcn_s_setprio(1);
        pv(1, pfB);
        __builtin_amdgcn_s_setprio(0);
    }

    // epilogue: O^T -> each lane holds dh=db*16+quad*4+r for its own q=l16.
    for (int qh = 0; qh < 2; qh++) {
        float v = ls[qh];
        v += __shfl_xor(v, 16);
        v += __shfl_xor(v, 32);           // full row sum for q=l16
        float rinv = 1.f / v;
        int qrow = qt * 128 + wave * 32 + qh * 16 + l16;
        for (int db = 0; db < 4; db++) {
            uint2 o;
            o.x = pkbf(O[db][qh][1] * rinv, O[db][qh][0] * rinv);
            o.y = pkbf(O[db][qh][3] * rinv, O[db][qh][2] * rinv);
            *(uint2*)&out[(size_t)(b * S + qrow) * D + h * 64 + db * 16 +
                          quad * 4] = o;
        }
    }
}

// ---------------------------------------------------------------------------
extern "C" void kernel_launch(void* const* d_in, const int* in_sizes, int n_in,
                              void* d_out, int out_size, void* d_ws, size_t ws_size,
                              hipStream_t stream) {
    const float* x     = (const float*)d_in[0];
    const float* w_in  = (const float*)d_in[1];
    const float* b_in  = (const float*)d_in[2];
    const float* w_out = (const float*)d_in[3];
    const float* b_out = (const float*)d_in[4];

    const int Bsz = 2, S = 2048, D = 1024, H = 16;
    const int M = Bsz * S;
    const int N1 = 3 * D;
    const float sc = 0.125f * 1.44269504f;  // 1/sqrt(64) * log2(e)

    u16* ws    = (u16*)d_ws;
    u16* Xb    = ws;
    u16* WtIn  = Xb + (size_t)M * D;
    u16* WtOut = WtIn + (size_t)N1 * D;
    u16* qkvb  = WtOut + (size_t)D * D;
    u16* attnb = qkvb + (size_t)M * N1;
    u16* Vt    = attnb + (size_t)M * D;    // fresh memory (gemm1 reads Xb)

    prep<<<8192, 256, 0, stream>>>(x, w_in, w_out, Xb, WtIn, WtOut);
    gemm_bt<128, 128><<<(M / 128) * (N1 / 128), 256, 0, stream>>>(
        Xb, WtIn, b_in, qkvb, M, N1, D, 0, D, sc, Vt, 2048);
    attn_kernel<<<512, 256, 0, stream>>>(qkvb, Vt, attnb);
    gemm_bt<64, 128><<<(M / 64) * (D / 128), 256, 0, stream>>>(
        attnb, WtOut, b_out, d_out, M, D, D, 1, 0, 1.f, nullptr, 1 << 30);
}